// Round 7
// baseline (11579.889 us; speedup 1.0000x reference)
//
#include <hip/hip_runtime.h>
#include <math.h>

#define NL 200
#define SLICE 131072ul  // 512 k * 256 b floats

// ---- workspace layout (float offsets), activations stored [k][b] ----
// BIG[201][512][256]: slice u+1 = sessionT[u]; GRU writes h_t = sseqT[t] at slice t.
#define BIG_OFF   0ul
#define LG_OFF    26345472ul   // logits [200][256]
#define ATT_OFF   26396672ul   // att    [200][256]
#define VT_OFF    26447872ul   // vtT    [512][256]
#define HBUF_OFF  26578944ul   // AUGRU h ping-pong [2][512][256]
#define HR_OFF    26841088ul   // r*h [512][256]
#define FLAGS_OFF 26972160ul   // u32 flags: gf[2][128] @0, af1[4][64] @256, af2[4][64] @512

__device__ __forceinline__ float sigmoidf_(float x) { return 1.0f / (1.0f + expf(-x)); }

// ---- LLC-direct (sc1) accessors: relaxed agent atomics, no fences ----
__device__ __forceinline__ float cohld1(const float* p) {
  return __hip_atomic_load(p, __ATOMIC_RELAXED, __HIP_MEMORY_SCOPE_AGENT);
}
__device__ __forceinline__ float2 cohld2(const float* p) {
  union { double d; float2 f; } u;
  u.d = __hip_atomic_load((const double*)p, __ATOMIC_RELAXED, __HIP_MEMORY_SCOPE_AGENT);
  return u.f;
}
__device__ __forceinline__ void cohst1(float* p, float v) {
  __hip_atomic_store(p, v, __ATOMIC_RELAXED, __HIP_MEMORY_SCOPE_AGENT);
}

// ---- grid waits: one wave polls flags (per-lane exit) ----
__device__ __forceinline__ void gwait64(const unsigned* f, unsigned val) {
  const int i = threadIdx.x & 63;
  int guard = 0;
  while (__hip_atomic_load(f + i, __ATOMIC_RELAXED, __HIP_MEMORY_SCOPE_AGENT) < val) {
    if (++guard > (1 << 22)) break;  // deadlock escape
  }
}
__device__ __forceinline__ void gwait128(const unsigned* f, unsigned val) {
  const int i = threadIdx.x & 63;
  bool d0 = false, d1 = false;
  int guard = 0;
  while (!(d0 && d1)) {
    if (!d0) d0 = __hip_atomic_load(f + i, __ATOMIC_RELAXED, __HIP_MEMORY_SCOPE_AGENT) >= val;
    if (!d1) d1 = __hip_atomic_load(f + i + 64, __ATOMIC_RELAXED, __HIP_MEMORY_SCOPE_AGENT) >= val;
    if (++guard > (1 << 22)) break;
  }
}

// ---- init: zero flags (graph replays => rerun every call) ----
__global__ void init_kernel(float* __restrict__ ws) {
  unsigned* const fl = (unsigned*)(ws + FLAGS_OFF);
  for (int j = threadIdx.x; j < 768; j += 256) fl[j] = 0u;
}

// ---- transpose session -> BIG slices 1..200 as [k][b] (sc1 stores) ----
__global__ __launch_bounds__(256) void transpose_kernel(const float* __restrict__ in,
                                                        float* __restrict__ ws) {
  __shared__ float tile[64][65];
  const int tx = threadIdx.x & 63, ty = threadIdx.x >> 6;
  const size_t tk0 = (size_t)blockIdx.x * 64;
  const int b0 = blockIdx.y * 64;
#pragma unroll
  for (int r = 0; r < 16; ++r) {
    const int bb = ty + 4 * r;
    tile[bb][tx] = in[(size_t)(b0 + bb) * 102400 + tk0 + tx];
  }
  __syncthreads();
  float* const big1 = ws + BIG_OFF + SLICE;
#pragma unroll
  for (int r = 0; r < 16; ++r) {
    const int kk = ty + 4 * r;
    cohst1(big1 + (tk0 + kk) * 256 + b0 + tx, tile[tx][kk]);
  }
}

// ---- vtT[d][b] = sum_e w[d,e] * target[b,e] ----
__global__ __launch_bounds__(256) void vt_kernel(const float* __restrict__ w,
                                                 const float* __restrict__ tgt,
                                                 float* __restrict__ ws) {
  __shared__ float t_s[512];
  const int b = blockIdx.x, tid = threadIdx.x;
  for (int i = tid; i < 512; i += 256) t_s[i] = tgt[(size_t)b * 512 + i];
  __syncthreads();
  const int wv = tid >> 6, lane = tid & 63;
  for (int d = wv; d < 512; d += 4) {
    const float* const wr = w + (size_t)d * 512;
    const float4 a  = *(const float4*)(wr + lane * 8);
    const float4 a2 = *(const float4*)(wr + lane * 8 + 4);
    float s = a.x * t_s[lane * 8 + 0] + a.y * t_s[lane * 8 + 1] +
              a.z * t_s[lane * 8 + 2] + a.w * t_s[lane * 8 + 3] +
              a2.x * t_s[lane * 8 + 4] + a2.y * t_s[lane * 8 + 5] +
              a2.z * t_s[lane * 8 + 6] + a2.w * t_s[lane * 8 + 7];
    for (int off = 32; off > 0; off >>= 1) s += __shfl_xor(s, off);
    if (lane == 0) ws[VT_OFF + (size_t)d * 256 + b] = s;
  }
}

// ---- persistent GRU: split-k over 8 waves; x-dot pipelined into wait window ----
__global__ __launch_bounds__(512) void gru_kernel(const float* __restrict__ wih,
                                                  const float* __restrict__ whh,
                                                  const float* __restrict__ bih,
                                                  const float* __restrict__ bhh,
                                                  float* __restrict__ ws) {
  __shared__ float wxT[512 * 16];   // [k][16]: slot g*4+q (12 used), broadcast reads
  __shared__ float whT[512 * 16];
  __shared__ float red[16 * 8 * 130];  // [slot][wave][128 rows +2 pad]
  __shared__ float bihs[12], bhhs[12];

  const int bg = blockIdx.x >> 7;   // batch half
  const int ng = blockIdx.x & 127;  // col group
  const int b0 = bg << 7, c0 = ng << 2;
  const int tid = threadIdx.x;

  for (int i = tid; i < 512 * 16; i += 512) {
    const int k = i >> 4, s = i & 15;
    if (s < 12) {
      const int grow = ((s >> 2) << 9) + c0 + (s & 3);
      wxT[i] = wih[(size_t)grow * 512 + k];
      whT[i] = whh[(size_t)grow * 512 + k];
    }
  }
  if (tid < 12) {
    const int grow = ((tid >> 2) << 9) + c0 + (tid & 3);
    bihs[tid] = bih[grow];
    bhhs[tid] = bhh[grow];
  }
  __syncthreads();

  float* const big = ws + BIG_OFF;
  unsigned* const gf = (unsigned*)(ws + FLAGS_OFF) + (bg << 7);

  const int wv = tid >> 6, l = tid & 63;
  const int k0 = wv << 6;
  const int boff = b0 + 2 * l;          // dot-stage: rows 2l,2l+1 (float2)
  const int qg = tid >> 7;              // gate-stage: col qg, row rr
  const int rr = tid & 127;
  const size_t og = (size_t)(c0 + qg) * 256 + b0 + rr;

  // ---- prologue: x-dot for t=0 (sessionT[0] = slice 1) ----
  float2 ax[12];
#pragma unroll
  for (int s = 0; s < 12; ++s) ax[s] = make_float2(0.0f, 0.0f);
  {
    const float* const xp = big + 1ul * SLICE + boff;
#pragma unroll
    for (int bq = 0; bq < 4; ++bq) {
      const int kb = k0 + bq * 16;
      float2 v[16];
#pragma unroll
      for (int j = 0; j < 16; ++j) v[j] = cohld2(xp + (size_t)(kb + j) * 256);
#pragma unroll
      for (int j = 0; j < 16; ++j) {
        const float4* const wr = (const float4*)(wxT + (size_t)(kb + j) * 16);
        float w12[12];
        *(float4*)&w12[0] = wr[0];
        *(float4*)&w12[4] = wr[1];
        *(float4*)&w12[8] = wr[2];
#pragma unroll
        for (int s = 0; s < 12; ++s) {
          ax[s].x += v[j].x * w12[s];
          ax[s].y += v[j].y * w12[s];
        }
      }
    }
  }

  for (int t = 0; t < NL; ++t) {
    // ---- grid wait ----
    if (t > 0) {
      if (wv == 0) gwait128(gf, (unsigned)t);
      __syncthreads();
    }
    // ---- h-dot (normal loads; fresh addresses each step -> L2-shared) ----
    float2 ah[12];
#pragma unroll
    for (int s = 0; s < 12; ++s) ah[s] = make_float2(0.0f, 0.0f);
    float hprev = 0.0f;
    if (t > 0) {
      const float* const hp = big + (size_t)(t - 1) * SLICE + boff;
      hprev = big[(size_t)(t - 1) * SLICE + og];  // prefetch for gate stage
#pragma unroll
      for (int bq = 0; bq < 4; ++bq) {
        const int kb = k0 + bq * 16;
        float2 v[16];
#pragma unroll
        for (int j = 0; j < 16; ++j) v[j] = *(const float2*)(hp + (size_t)(kb + j) * 256);
#pragma unroll
        for (int j = 0; j < 16; ++j) {
          const float4* const wr = (const float4*)(whT + (size_t)(kb + j) * 16);
          float w12[12];
          *(float4*)&w12[0] = wr[0];
          *(float4*)&w12[4] = wr[1];
          *(float4*)&w12[8] = wr[2];
#pragma unroll
          for (int s = 0; s < 12; ++s) {
            ah[s].x += v[j].x * w12[s];
            ah[s].y += v[j].y * w12[s];
          }
        }
      }
    }
    // ---- cross-wave reduce: slots 0-3 r(x+h), 4-7 z(x+h), 8-11 xn, 12-15 hn ----
#pragma unroll
    for (int s = 0; s < 4; ++s) {
      *(float2*)&red[((size_t)(0 + s) * 8 + wv) * 130 + 2 * l] =
          make_float2(ax[s].x + ah[s].x, ax[s].y + ah[s].y);
      *(float2*)&red[((size_t)(4 + s) * 8 + wv) * 130 + 2 * l] =
          make_float2(ax[4 + s].x + ah[4 + s].x, ax[4 + s].y + ah[4 + s].y);
      *(float2*)&red[((size_t)(8 + s) * 8 + wv) * 130 + 2 * l] = ax[8 + s];
      *(float2*)&red[((size_t)(12 + s) * 8 + wv) * 130 + 2 * l] = ah[8 + s];
    }
    __syncthreads();
    // ---- gates: thread -> (col qg, row rr) ----
    float rp = 0, zp = 0, xnp = 0, hnp = 0;
#pragma unroll
    for (int w8 = 0; w8 < 8; ++w8) {
      rp  += red[((size_t)(0 + qg) * 8 + w8) * 130 + rr];
      zp  += red[((size_t)(4 + qg) * 8 + w8) * 130 + rr];
      xnp += red[((size_t)(8 + qg) * 8 + w8) * 130 + rr];
      hnp += red[((size_t)(12 + qg) * 8 + w8) * 130 + rr];
    }
    const float r = sigmoidf_(rp + bihs[0 + qg] + bhhs[0 + qg]);
    const float z = sigmoidf_(zp + bihs[4 + qg] + bhhs[4 + qg]);
    const float n = tanhf(xnp + bihs[8 + qg] + r * (hnp + bhhs[8 + qg]));
    const float hnew = (1.0f - z) * n + z * hprev;
    cohst1(big + (size_t)t * SLICE + og, hnew);
    // ---- arrive ----
    asm volatile("s_waitcnt vmcnt(0)" ::: "memory");
    __syncthreads();
    if (tid == 0)
      __hip_atomic_store(gf + ng, (unsigned)(t + 1), __ATOMIC_RELAXED, __HIP_MEMORY_SCOPE_AGENT);
    // ---- pipelined x-dot for t+1 (hides in other blocks' tail + our wait) ----
    if (t + 1 < NL) {
      const float* const xp = big + (size_t)(t + 2) * SLICE + boff;  // sessionT[t+1]
#pragma unroll
      for (int s = 0; s < 12; ++s) ax[s] = make_float2(0.0f, 0.0f);
#pragma unroll
      for (int bq = 0; bq < 4; ++bq) {
        const int kb = k0 + bq * 16;
        float2 v[16];
#pragma unroll
        for (int j = 0; j < 16; ++j) v[j] = cohld2(xp + (size_t)(kb + j) * 256);
#pragma unroll
        for (int j = 0; j < 16; ++j) {
          const float4* const wr = (const float4*)(wxT + (size_t)(kb + j) * 16);
          float w12[12];
          *(float4*)&w12[0] = wr[0];
          *(float4*)&w12[4] = wr[1];
          *(float4*)&w12[8] = wr[2];
#pragma unroll
          for (int s = 0; s < 12; ++s) {
            ax[s].x += v[j].x * w12[s];
            ax[s].y += v[j].y * w12[s];
          }
        }
      }
    }
    asm volatile("" ::: "memory");
  }
}

// ---- attn1: logits[l][b] = sum_k sseqT[l][k][b] * vtT[k][b] ----
__global__ __launch_bounds__(256) void attn1_kernel(float* __restrict__ ws) {
  const int l = blockIdx.x, tid = threadIdx.x;
  const float* const sl = ws + BIG_OFF + (size_t)l * SLICE + tid;
  const float* const vtt = ws + VT_OFF + tid;
  float acc = 0.0f;
#pragma unroll 8
  for (int k = 0; k < 512; ++k)
    acc += sl[(size_t)k * 256] * vtt[(size_t)k * 256];
  ws[LG_OFF + (size_t)l * 256 + tid] = acc;
}

// ---- attn2: softmax over l per batch row; write attT[l][b] ----
__global__ __launch_bounds__(256) void attn2_kernel(float* __restrict__ ws) {
  __shared__ float red[8];
  const int b = blockIdx.x, tid = threadIdx.x;
  const float v = (tid < NL) ? ws[LG_OFF + (size_t)tid * 256 + b] : -3.0e38f;
  float m = v;
  for (int off = 32; off > 0; off >>= 1) m = fmaxf(m, __shfl_xor(m, off));
  if ((tid & 63) == 0) red[tid >> 6] = m;
  __syncthreads();
  m = fmaxf(fmaxf(red[0], red[1]), fmaxf(red[2], red[3]));
  const float e = (tid < NL) ? expf(v - m) : 0.0f;
  float s = e;
  for (int off = 32; off > 0; off >>= 1) s += __shfl_xor(s, off);
  __syncthreads();
  if ((tid & 63) == 0) red[4 + (tid >> 6)] = s;
  __syncthreads();
  s = red[4] + red[5] + red[6] + red[7];
  if (tid < NL) ws[ATT_OFF + (size_t)tid * 256 + b] = e / s;
}

// ---- persistent AUGRU: split-k over 8 waves; x-dot pipelined into af1 window ----
__global__ __launch_bounds__(512) void augru_kernel(const float* __restrict__ rw,
                                                    const float* __restrict__ rbias,
                                                    const float* __restrict__ uw,
                                                    const float* __restrict__ ubias,
                                                    const float* __restrict__ hw,
                                                    const float* __restrict__ hbias,
                                                    float* __restrict__ ws,
                                                    float* __restrict__ out) {
  __shared__ float wT[1024 * 24];     // [k][24]: slot m*8+c (m: 0=r,1=u,2=hhat)
  __shared__ float red[24 * 8 * 66];  // [slot][wave][64 rows +2 pad]
  __shared__ float rbs[8], ubs[8], hbs[8];

  const int rg = blockIdx.x >> 6;   // row group (64 rows)
  const int cg = blockIdx.x & 63;   // col group (8 cols)
  const int r0 = rg << 6, c0 = cg << 3;
  const int tid = threadIdx.x;

  for (int m = 0; m < 3; ++m) {
    const float* const wm = (m == 0) ? rw : (m == 1) ? uw : hw;
    for (int i = tid; i < 8192; i += 512) {
      const int k = i >> 3, c = i & 7;
      wT[(size_t)k * 24 + m * 8 + c] = wm[(size_t)(c0 + c) * 1024 + k];
    }
  }
  if (tid < 8) {
    rbs[tid] = rbias[c0 + tid];
    ubs[tid] = ubias[c0 + tid];
    hbs[tid] = hbias[c0 + tid];
  }
  __syncthreads();

  float* const big = ws + BIG_OFF;
  float* const hbuf = ws + HBUF_OFF;
  float* const hrg = ws + HR_OFF;
  const float* const att = ws + ATT_OFF;
  unsigned* const fbase = (unsigned*)(ws + FLAGS_OFF);
  unsigned* const af1 = fbase + 256 + (rg << 6);
  unsigned* const af2 = fbase + 512 + (rg << 6);

  const int wv = tid >> 6, l = tid & 63;
  const int k0 = wv << 6;
  const int boff = r0 + l;            // dot-stage: 1 row per lane
  const int cq = tid >> 6;            // gate-stage: col cq, row rr
  const int rr = tid & 63;
  const size_t og = (size_t)(c0 + cq) * 256 + r0 + rr;

  // ---- prologue: x-dot for t=0 (sseqT[0] = slice 0; normal/L2 loads) ----
  float ax[24];
#pragma unroll
  for (int s = 0; s < 24; ++s) ax[s] = 0.0f;
  {
    const float* const xp = big + boff;
#pragma unroll
    for (int bq = 0; bq < 4; ++bq) {
      const int kb = k0 + bq * 16;
      float v[16];
#pragma unroll
      for (int j = 0; j < 16; ++j) v[j] = xp[(size_t)(kb + j) * 256];
#pragma unroll
      for (int j = 0; j < 16; ++j) {
        const float4* const wr = (const float4*)(wT + (size_t)(512 + kb + j) * 24);
        float w24[24];
        *(float4*)&w24[0] = wr[0];  *(float4*)&w24[4] = wr[1];
        *(float4*)&w24[8] = wr[2];  *(float4*)&w24[12] = wr[3];
        *(float4*)&w24[16] = wr[4]; *(float4*)&w24[20] = wr[5];
#pragma unroll
        for (int s = 0; s < 24; ++s) ax[s] += v[j] * w24[s];
      }
    }
  }

  for (int t = 0; t < NL; ++t) {
    // ---- wait previous step's phase2 ----
    if (t > 0) {
      if (wv == 0) gwait64(af2, (unsigned)t);
      __syncthreads();
    }
    // ---- phase1 h-dot: r,u (sc1; h src = GRU final at t=0, else ping-pong) ----
    const float* const hsrc = (t == 0) ? (big + 199ul * SLICE) : (hbuf + (size_t)(t & 1) * SLICE);
    const float hcur = cohld1(hsrc + og);
    float ah[16];
#pragma unroll
    for (int s = 0; s < 16; ++s) ah[s] = 0.0f;
    {
      const float* const hp = hsrc + boff;
#pragma unroll
      for (int bq = 0; bq < 4; ++bq) {
        const int kb = k0 + bq * 16;
        float v[16];
#pragma unroll
        for (int j = 0; j < 16; ++j) v[j] = cohld1(hp + (size_t)(kb + j) * 256);
#pragma unroll
        for (int j = 0; j < 16; ++j) {
          const float4* const wr = (const float4*)(wT + (size_t)(kb + j) * 24);
          float w16[16];
          *(float4*)&w16[0] = wr[0];  *(float4*)&w16[4] = wr[1];
          *(float4*)&w16[8] = wr[2];  *(float4*)&w16[12] = wr[3];
#pragma unroll
          for (int s = 0; s < 16; ++s) ah[s] += v[j] * w16[s];
        }
      }
    }
    // ---- reduce phase1: slots 0-7 r(x+h), 8-15 u(x+h), 16-23 xh ----
#pragma unroll
    for (int c = 0; c < 8; ++c) {
      red[((size_t)(0 + c) * 8 + wv) * 66 + l] = ax[c] + ah[c];
      red[((size_t)(8 + c) * 8 + wv) * 66 + l] = ax[8 + c] + ah[8 + c];
      red[((size_t)(16 + c) * 8 + wv) * 66 + l] = ax[16 + c];
    }
    __syncthreads();
    float rp = 0, up = 0, xhp = 0;
#pragma unroll
    for (int w8 = 0; w8 < 8; ++w8) {
      rp  += red[((size_t)(0 + cq) * 8 + w8) * 66 + rr];
      up  += red[((size_t)(8 + cq) * 8 + w8) * 66 + rr];
      xhp += red[((size_t)(16 + cq) * 8 + w8) * 66 + rr];
    }
    const float rgate = sigmoidf_(rp + rbs[cq]);
    const float ug = sigmoidf_(up + ubs[cq]);
    cohst1(hrg + og, rgate * hcur);
    asm volatile("s_waitcnt vmcnt(0)" ::: "memory");
    __syncthreads();
    if (tid == 0)
      __hip_atomic_store(af1 + cg, (unsigned)(t + 1), __ATOMIC_RELAXED, __HIP_MEMORY_SCOPE_AGENT);
    // ---- pipelined x-dot for t+1 (hides the af1 round-trip) ----
    if (t + 1 < NL) {
      const float* const xp = big + (size_t)(t + 1) * SLICE + boff;
#pragma unroll
      for (int s = 0; s < 24; ++s) ax[s] = 0.0f;
#pragma unroll
      for (int bq = 0; bq < 4; ++bq) {
        const int kb = k0 + bq * 16;
        float v[16];
#pragma unroll
        for (int j = 0; j < 16; ++j) v[j] = xp[(size_t)(kb + j) * 256];
#pragma unroll
        for (int j = 0; j < 16; ++j) {
          const float4* const wr = (const float4*)(wT + (size_t)(512 + kb + j) * 24);
          float w24[24];
          *(float4*)&w24[0] = wr[0];  *(float4*)&w24[4] = wr[1];
          *(float4*)&w24[8] = wr[2];  *(float4*)&w24[12] = wr[3];
          *(float4*)&w24[16] = wr[4]; *(float4*)&w24[20] = wr[5];
#pragma unroll
          for (int s = 0; s < 24; ++s) ax[s] += v[j] * w24[s];
        }
      }
    }
    asm volatile("" ::: "memory");
    if (wv == 0) gwait64(af1, (unsigned)(t + 1));
    __syncthreads();
    // ---- phase2 hr-dot: hhat (sc1) ----
    float ahh[8];
#pragma unroll
    for (int s = 0; s < 8; ++s) ahh[s] = 0.0f;
    {
      const float* const rp2 = hrg + boff;
#pragma unroll
      for (int bq = 0; bq < 4; ++bq) {
        const int kb = k0 + bq * 16;
        float v[16];
#pragma unroll
        for (int j = 0; j < 16; ++j) v[j] = cohld1(rp2 + (size_t)(kb + j) * 256);
#pragma unroll
        for (int j = 0; j < 16; ++j) {
          const float4* const wr = (const float4*)(wT + (size_t)(kb + j) * 24);
          float w8a[8];
          *(float4*)&w8a[0] = wr[4];
          *(float4*)&w8a[4] = wr[5];
#pragma unroll
          for (int s = 0; s < 8; ++s) ahh[s] += v[j] * w8a[s];
        }
      }
    }
#pragma unroll
    for (int c = 0; c < 8; ++c)
      red[((size_t)c * 8 + wv) * 66 + l] = ahh[c];
    __syncthreads();
    float hhp = 0;
#pragma unroll
    for (int w8 = 0; w8 < 8; ++w8)
      hhp += red[((size_t)cq * 8 + w8) * 66 + rr];
    const float hh = tanhf(hhp + xhp + hbs[cq]);
    const float av = att[(size_t)t * 256 + r0 + rr];
    const float u = av * ug;
    const float hn = (1.0f - u) * hcur + u * hh;
    if (t == NL - 1) {
      out[(size_t)(r0 + rr) * 512 + c0 + cq] = hn;
    } else {
      cohst1(hbuf + (size_t)((t + 1) & 1) * SLICE + og, hn);
    }
    asm volatile("s_waitcnt vmcnt(0)" ::: "memory");
    __syncthreads();
    if (tid == 0)
      __hip_atomic_store(af2 + cg, (unsigned)(t + 1), __ATOMIC_RELAXED, __HIP_MEMORY_SCOPE_AGENT);
  }
}

extern "C" void kernel_launch(void* const* d_in, const int* in_sizes, int n_in,
                              void* d_out, int out_size, void* d_ws, size_t ws_size,
                              hipStream_t stream) {
  (void)in_sizes; (void)n_in; (void)out_size; (void)ws_size;
  const float* session = (const float*)d_in[0];
  const float* target  = (const float*)d_in[1];
  const float* w       = (const float*)d_in[2];
  const float* wih     = (const float*)d_in[3];
  const float* whh     = (const float*)d_in[4];
  const float* bih     = (const float*)d_in[5];
  const float* bhh     = (const float*)d_in[6];
  const float* rw      = (const float*)d_in[7];
  const float* rb      = (const float*)d_in[8];
  const float* uw      = (const float*)d_in[9];
  const float* ub      = (const float*)d_in[10];
  const float* hw      = (const float*)d_in[11];
  const float* hb      = (const float*)d_in[12];
  float* ws  = (float*)d_ws;
  float* out = (float*)d_out;

  hipLaunchKernelGGL(init_kernel, dim3(1), dim3(256), 0, stream, ws);
  hipLaunchKernelGGL(transpose_kernel, dim3(1600, 4), dim3(256), 0, stream, session, ws);
  hipLaunchKernelGGL(vt_kernel, dim3(256), dim3(256), 0, stream, w, target, ws);
  hipLaunchKernelGGL(gru_kernel, dim3(256), dim3(512), 0, stream,
                     wih, whh, bih, bhh, ws);
  hipLaunchKernelGGL(attn1_kernel, dim3(200), dim3(256), 0, stream, ws);
  hipLaunchKernelGGL(attn2_kernel, dim3(256), dim3(256), 0, stream, ws);
  hipLaunchKernelGGL(augru_kernel, dim3(256), dim3(512), 0, stream,
                     rw, rb, uw, ub, hw, hb, ws, out);
}

// Round 8
// 7197.231 us; speedup vs baseline: 1.6089x; 1.6089x over previous
//
#include <hip/hip_runtime.h>
#include <math.h>

#define NL 200
#define SLICE 131072ul  // 512 k * 256 b floats

// ---- workspace layout (float offsets), activations stored [k][b] ----
// BIG[201][512][256]: slice u+1 = sessionT[u]; GRU writes h_t = sseqT[t] at slice t.
#define BIG_OFF   0ul
#define LG_OFF    26345472ul   // logits [200][256]
#define ATT_OFF   26396672ul   // att    [200][256]
#define VT_OFF    26447872ul   // vtT    [512][256]
#define HBUF_OFF  26578944ul   // AUGRU h ping-pong [2][512][256] (fallback mode)
#define HR_OFF    26841088ul   // r*h [512][256] (fallback mode)
#define FLAGS_OFF 26972160ul   // u32 flags: gf[2][128] @0, af1[4][64] @256, af2[4][64] @512
// expanded mode (used only when ws_size is large enough):
#define HAUG_OFF  26973184ul                     // h[t]  : [200][512][256]
#define HRAUG_OFF (HAUG_OFF + 200ul * SLICE)     // hr[t] : [200][512][256]
#define WS_NEED_FLOATS (HRAUG_OFF + 200ul * SLICE)

__device__ __forceinline__ float sigmoidf_(float x) { return 1.0f / (1.0f + expf(-x)); }

// ---- LLC-direct (sc1) accessors: relaxed agent atomics, no fences ----
__device__ __forceinline__ float cohld1(const float* p) {
  return __hip_atomic_load(p, __ATOMIC_RELAXED, __HIP_MEMORY_SCOPE_AGENT);
}
__device__ __forceinline__ float2 cohld2(const float* p) {
  union { double d; float2 f; } u;
  u.d = __hip_atomic_load((const double*)p, __ATOMIC_RELAXED, __HIP_MEMORY_SCOPE_AGENT);
  return u.f;
}
__device__ __forceinline__ void cohst1(float* p, float v) {
  __hip_atomic_store(p, v, __ATOMIC_RELAXED, __HIP_MEMORY_SCOPE_AGENT);
}

// ---- grid waits: one wave polls flags (per-lane exit) ----
__device__ __forceinline__ void gwait64(const unsigned* f, unsigned val) {
  const int i = threadIdx.x & 63;
  int guard = 0;
  while (__hip_atomic_load(f + i, __ATOMIC_RELAXED, __HIP_MEMORY_SCOPE_AGENT) < val) {
    if (++guard > (1 << 22)) break;  // deadlock escape
  }
}
__device__ __forceinline__ void gwait128(const unsigned* f, unsigned val) {
  const int i = threadIdx.x & 63;
  bool d0 = false, d1 = false;
  int guard = 0;
  while (!(d0 && d1)) {
    if (!d0) d0 = __hip_atomic_load(f + i, __ATOMIC_RELAXED, __HIP_MEMORY_SCOPE_AGENT) >= val;
    if (!d1) d1 = __hip_atomic_load(f + i + 64, __ATOMIC_RELAXED, __HIP_MEMORY_SCOPE_AGENT) >= val;
    if (++guard > (1 << 22)) break;
  }
}

// ---- init: zero flags (graph replays => rerun every call) ----
__global__ void init_kernel(float* __restrict__ ws) {
  unsigned* const fl = (unsigned*)(ws + FLAGS_OFF);
  for (int j = threadIdx.x; j < 768; j += 256) fl[j] = 0u;
}

// ---- transpose session -> BIG slices 1..200 as [k][b] (sc1 stores) ----
__global__ __launch_bounds__(256) void transpose_kernel(const float* __restrict__ in,
                                                        float* __restrict__ ws) {
  __shared__ float tile[64][65];
  const int tx = threadIdx.x & 63, ty = threadIdx.x >> 6;
  const size_t tk0 = (size_t)blockIdx.x * 64;
  const int b0 = blockIdx.y * 64;
#pragma unroll
  for (int r = 0; r < 16; ++r) {
    const int bb = ty + 4 * r;
    tile[bb][tx] = in[(size_t)(b0 + bb) * 102400 + tk0 + tx];
  }
  __syncthreads();
  float* const big1 = ws + BIG_OFF + SLICE;
#pragma unroll
  for (int r = 0; r < 16; ++r) {
    const int kk = ty + 4 * r;
    cohst1(big1 + (tk0 + kk) * 256 + b0 + tx, tile[tx][kk]);
  }
}

// ---- vtT[d][b] = sum_e w[d,e] * target[b,e] ----
__global__ __launch_bounds__(256) void vt_kernel(const float* __restrict__ w,
                                                 const float* __restrict__ tgt,
                                                 float* __restrict__ ws) {
  __shared__ float t_s[512];
  const int b = blockIdx.x, tid = threadIdx.x;
  for (int i = tid; i < 512; i += 256) t_s[i] = tgt[(size_t)b * 512 + i];
  __syncthreads();
  const int wv = tid >> 6, lane = tid & 63;
  for (int d = wv; d < 512; d += 4) {
    const float* const wr = w + (size_t)d * 512;
    const float4 a  = *(const float4*)(wr + lane * 8);
    const float4 a2 = *(const float4*)(wr + lane * 8 + 4);
    float s = a.x * t_s[lane * 8 + 0] + a.y * t_s[lane * 8 + 1] +
              a.z * t_s[lane * 8 + 2] + a.w * t_s[lane * 8 + 3] +
              a2.x * t_s[lane * 8 + 4] + a2.y * t_s[lane * 8 + 5] +
              a2.z * t_s[lane * 8 + 6] + a2.w * t_s[lane * 8 + 7];
    for (int off = 32; off > 0; off >>= 1) s += __shfl_xor(s, off);
    if (lane == 0) ws[VT_OFF + (size_t)d * 256 + b] = s;
  }
}

// ---- persistent GRU: split-k over 8 waves; x-dot(t+1) after flag post ----
__global__ __launch_bounds__(512) void gru_kernel(const float* __restrict__ wih,
                                                  const float* __restrict__ whh,
                                                  const float* __restrict__ bih,
                                                  const float* __restrict__ bhh,
                                                  float* __restrict__ ws) {
  __shared__ float wxT[512 * 16];   // [k][16]: slot g*4+q (12 used), broadcast reads
  __shared__ float whT[512 * 16];
  __shared__ float red[16 * 8 * 130];  // [slot][wave][128 rows +2 pad]
  __shared__ float bihs[12], bhhs[12];

  const int bg = blockIdx.x >> 7;   // batch half
  const int ng = blockIdx.x & 127;  // col group
  const int b0 = bg << 7, c0 = ng << 2;
  const int tid = threadIdx.x;

  for (int i = tid; i < 512 * 16; i += 512) {
    const int k = i >> 4, s = i & 15;
    if (s < 12) {
      const int grow = ((s >> 2) << 9) + c0 + (s & 3);
      wxT[i] = wih[(size_t)grow * 512 + k];
      whT[i] = whh[(size_t)grow * 512 + k];
    }
  }
  if (tid < 12) {
    const int grow = ((tid >> 2) << 9) + c0 + (tid & 3);
    bihs[tid] = bih[grow];
    bhhs[tid] = bhh[grow];
  }
  __syncthreads();

  float* const big = ws + BIG_OFF;
  unsigned* const gf = (unsigned*)(ws + FLAGS_OFF) + (bg << 7);

  const int wv = tid >> 6, l = tid & 63;
  const int k0 = wv << 6;
  const int boff = b0 + 2 * l;          // dot-stage: rows 2l,2l+1 (float2)
  const int qg = tid >> 7;              // gate-stage: col qg, row rr
  const int rr = tid & 127;
  const size_t og = (size_t)(c0 + qg) * 256 + b0 + rr;

  // ---- prologue: x-dot for t=0 (sessionT[0] = slice 1) ----
  float2 ax[12];
#pragma unroll
  for (int s = 0; s < 12; ++s) ax[s] = make_float2(0.0f, 0.0f);
  {
    const float* const xp = big + 1ul * SLICE + boff;
    for (int bq = 0; bq < 4; ++bq) {
      const int kb = k0 + bq * 16;
      float2 v[16];
#pragma unroll
      for (int j = 0; j < 16; ++j) v[j] = cohld2(xp + (size_t)(kb + j) * 256);
#pragma unroll
      for (int j = 0; j < 16; ++j) {
        const float4* const wr = (const float4*)(wxT + (size_t)(kb + j) * 16);
        float w12[12];
        *(float4*)&w12[0] = wr[0];
        *(float4*)&w12[4] = wr[1];
        *(float4*)&w12[8] = wr[2];
#pragma unroll
        for (int s = 0; s < 12; ++s) {
          ax[s].x += v[j].x * w12[s];
          ax[s].y += v[j].y * w12[s];
        }
      }
    }
  }

  for (int t = 0; t < NL; ++t) {
    // ---- grid wait ----
    if (t > 0) {
      if (wv == 0) gwait128(gf, (unsigned)t);
      __syncthreads();
    }
    // ---- h-dot (normal loads; fresh addresses each step -> L2-shared) ----
    float2 ah[12];
#pragma unroll
    for (int s = 0; s < 12; ++s) ah[s] = make_float2(0.0f, 0.0f);
    float hprev = 0.0f;
    if (t > 0) {
      const float* const hp = big + (size_t)(t - 1) * SLICE + boff;
      hprev = big[(size_t)(t - 1) * SLICE + og];  // prefetch for gate stage
      for (int bq = 0; bq < 4; ++bq) {
        const int kb = k0 + bq * 16;
        float2 v[16];
#pragma unroll
        for (int j = 0; j < 16; ++j) v[j] = *(const float2*)(hp + (size_t)(kb + j) * 256);
#pragma unroll
        for (int j = 0; j < 16; ++j) {
          const float4* const wr = (const float4*)(whT + (size_t)(kb + j) * 16);
          float w12[12];
          *(float4*)&w12[0] = wr[0];
          *(float4*)&w12[4] = wr[1];
          *(float4*)&w12[8] = wr[2];
#pragma unroll
          for (int s = 0; s < 12; ++s) {
            ah[s].x += v[j].x * w12[s];
            ah[s].y += v[j].y * w12[s];
          }
        }
      }
    }
    // ---- cross-wave reduce: slots 0-3 r(x+h), 4-7 z(x+h), 8-11 xn, 12-15 hn ----
#pragma unroll
    for (int s = 0; s < 4; ++s) {
      *(float2*)&red[((size_t)(0 + s) * 8 + wv) * 130 + 2 * l] =
          make_float2(ax[s].x + ah[s].x, ax[s].y + ah[s].y);
      *(float2*)&red[((size_t)(4 + s) * 8 + wv) * 130 + 2 * l] =
          make_float2(ax[4 + s].x + ah[4 + s].x, ax[4 + s].y + ah[4 + s].y);
      *(float2*)&red[((size_t)(8 + s) * 8 + wv) * 130 + 2 * l] = ax[8 + s];
      *(float2*)&red[((size_t)(12 + s) * 8 + wv) * 130 + 2 * l] = ah[8 + s];
    }
    __syncthreads();
    // ---- gates: thread -> (col qg, row rr) ----
    float rp = 0, zp = 0, xnp = 0, hnp = 0;
#pragma unroll
    for (int w8 = 0; w8 < 8; ++w8) {
      rp  += red[((size_t)(0 + qg) * 8 + w8) * 130 + rr];
      zp  += red[((size_t)(4 + qg) * 8 + w8) * 130 + rr];
      xnp += red[((size_t)(8 + qg) * 8 + w8) * 130 + rr];
      hnp += red[((size_t)(12 + qg) * 8 + w8) * 130 + rr];
    }
    const float r = sigmoidf_(rp + bihs[0 + qg] + bhhs[0 + qg]);
    const float z = sigmoidf_(zp + bihs[4 + qg] + bhhs[4 + qg]);
    const float n = tanhf(xnp + bihs[8 + qg] + r * (hnp + bhhs[8 + qg]));
    const float hnew = (1.0f - z) * n + z * hprev;
    cohst1(big + (size_t)t * SLICE + og, hnew);
    // ---- arrive ----
    asm volatile("s_waitcnt vmcnt(0)" ::: "memory");
    __syncthreads();
    if (tid == 0)
      __hip_atomic_store(gf + ng, (unsigned)(t + 1), __ATOMIC_RELAXED, __HIP_MEMORY_SCOPE_AGENT);
    // ---- pipelined x-dot for t+1 (after post: hides flag propagation) ----
    if (t + 1 < NL) {
      const float* const xp = big + (size_t)(t + 2) * SLICE + boff;  // sessionT[t+1]
#pragma unroll
      for (int s = 0; s < 12; ++s) ax[s] = make_float2(0.0f, 0.0f);
      for (int bq = 0; bq < 4; ++bq) {
        const int kb = k0 + bq * 16;
        float2 v[16];
#pragma unroll
        for (int j = 0; j < 16; ++j) v[j] = cohld2(xp + (size_t)(kb + j) * 256);
#pragma unroll
        for (int j = 0; j < 16; ++j) {
          const float4* const wr = (const float4*)(wxT + (size_t)(kb + j) * 16);
          float w12[12];
          *(float4*)&w12[0] = wr[0];
          *(float4*)&w12[4] = wr[1];
          *(float4*)&w12[8] = wr[2];
#pragma unroll
          for (int s = 0; s < 12; ++s) {
            ax[s].x += v[j].x * w12[s];
            ax[s].y += v[j].y * w12[s];
          }
        }
      }
    }
    asm volatile("" ::: "memory");
  }
}

// ---- attn1: logits[l][b] = sum_k sseqT[l][k][b] * vtT[k][b] ----
__global__ __launch_bounds__(256) void attn1_kernel(float* __restrict__ ws) {
  const int l = blockIdx.x, tid = threadIdx.x;
  const float* const sl = ws + BIG_OFF + (size_t)l * SLICE + tid;
  const float* const vtt = ws + VT_OFF + tid;
  float acc = 0.0f;
#pragma unroll 8
  for (int k = 0; k < 512; ++k)
    acc += sl[(size_t)k * 256] * vtt[(size_t)k * 256];
  ws[LG_OFF + (size_t)l * 256 + tid] = acc;
}

// ---- attn2: softmax over l per batch row; write attT[l][b] ----
__global__ __launch_bounds__(256) void attn2_kernel(float* __restrict__ ws) {
  __shared__ float red[8];
  const int b = blockIdx.x, tid = threadIdx.x;
  const float v = (tid < NL) ? ws[LG_OFF + (size_t)tid * 256 + b] : -3.0e38f;
  float m = v;
  for (int off = 32; off > 0; off >>= 1) m = fmaxf(m, __shfl_xor(m, off));
  if ((tid & 63) == 0) red[tid >> 6] = m;
  __syncthreads();
  m = fmaxf(fmaxf(red[0], red[1]), fmaxf(red[2], red[3]));
  const float e = (tid < NL) ? expf(v - m) : 0.0f;
  float s = e;
  for (int off = 32; off > 0; off >>= 1) s += __shfl_xor(s, off);
  __syncthreads();
  if ((tid & 63) == 0) red[4 + (tid >> 6)] = s;
  __syncthreads();
  s = red[4] + red[5] + red[6] + red[7];
  if (tid < NL) ws[ATT_OFF + (size_t)tid * 256 + b] = e / s;
}

// ---- persistent AUGRU: split-k over 8 waves; x-dot in af1 window.
// EXP=true: h[t]/hr[t] in fresh per-step slices -> normal L2-cached reads.
// EXP=false: r6 sc1 ping-pong fallback. Writes always sc1 (write-through). ----
template <bool EXP>
__global__ __launch_bounds__(512) void augru_kernel(const float* __restrict__ rw,
                                                    const float* __restrict__ rbias,
                                                    const float* __restrict__ uw,
                                                    const float* __restrict__ ubias,
                                                    const float* __restrict__ hw,
                                                    const float* __restrict__ hbias,
                                                    float* __restrict__ ws,
                                                    float* __restrict__ out) {
  __shared__ float wT[1024 * 24];     // [k][24]: slot m*8+c (m: 0=r,1=u,2=hhat)
  __shared__ float red[24 * 8 * 66];  // [slot][wave][64 rows +2 pad]
  __shared__ float rbs[8], ubs[8], hbs[8];

  const int rg = blockIdx.x >> 6;   // row group (64 rows)
  const int cg = blockIdx.x & 63;   // col group (8 cols)
  const int r0 = rg << 6, c0 = cg << 3;
  const int tid = threadIdx.x;

  for (int m = 0; m < 3; ++m) {
    const float* const wm = (m == 0) ? rw : (m == 1) ? uw : hw;
    for (int i = tid; i < 8192; i += 512) {
      const int k = i >> 3, c = i & 7;
      wT[(size_t)k * 24 + m * 8 + c] = wm[(size_t)(c0 + c) * 1024 + k];
    }
  }
  if (tid < 8) {
    rbs[tid] = rbias[c0 + tid];
    ubs[tid] = ubias[c0 + tid];
    hbs[tid] = hbias[c0 + tid];
  }
  __syncthreads();

  float* const big = ws + BIG_OFF;
  float* const hbuf = ws + HBUF_OFF;
  float* const hrg = ws + HR_OFF;
  float* const haug = ws + HAUG_OFF;
  float* const hraug = ws + HRAUG_OFF;
  const float* const att = ws + ATT_OFF;
  unsigned* const fbase = (unsigned*)(ws + FLAGS_OFF);
  unsigned* const af1 = fbase + 256 + (rg << 6);
  unsigned* const af2 = fbase + 512 + (rg << 6);

  const int wv = tid >> 6, l = tid & 63;
  const int k0 = wv << 6;
  const int boff = r0 + l;            // dot-stage: 1 row per lane
  const int cq = tid >> 6;            // gate-stage: col cq, row rr
  const int rr = tid & 63;
  const size_t og = (size_t)(c0 + cq) * 256 + r0 + rr;

  // ---- prologue: x-dot for t=0 (sseqT[0] = slice 0; normal/L2 loads) ----
  float ax[24];
#pragma unroll
  for (int s = 0; s < 24; ++s) ax[s] = 0.0f;
  {
    const float* const xp = big + boff;
    for (int bq = 0; bq < 4; ++bq) {
      const int kb = k0 + bq * 16;
      float v[16];
#pragma unroll
      for (int j = 0; j < 16; ++j) v[j] = xp[(size_t)(kb + j) * 256];
#pragma unroll
      for (int j = 0; j < 16; ++j) {
        const float4* const wr = (const float4*)(wT + (size_t)(512 + kb + j) * 24);
        float w24[24];
        *(float4*)&w24[0] = wr[0];  *(float4*)&w24[4] = wr[1];
        *(float4*)&w24[8] = wr[2];  *(float4*)&w24[12] = wr[3];
        *(float4*)&w24[16] = wr[4]; *(float4*)&w24[20] = wr[5];
#pragma unroll
        for (int s = 0; s < 24; ++s) ax[s] += v[j] * w24[s];
      }
    }
  }

  for (int t = 0; t < NL; ++t) {
    // ---- wait previous step's phase2 ----
    if (t > 0) {
      if (wv == 0) gwait64(af2, (unsigned)t);
      __syncthreads();
    }
    // ---- phase1 h-dot: r,u. h src: t=0 -> GRU final (big[199]);
    // EXP: haug[t-1] (normal loads); else hbuf ping-pong (sc1) ----
    const float* const hsrc =
        (t == 0) ? (big + 199ul * SLICE)
                 : (EXP ? (haug + (size_t)(t - 1) * SLICE)
                        : (hbuf + (size_t)(t & 1) * SLICE));
    float hcur;
    if (EXP) hcur = hsrc[og]; else hcur = cohld1(hsrc + og);
    float ah[16];
#pragma unroll
    for (int s = 0; s < 16; ++s) ah[s] = 0.0f;
    {
      const float* const hp = hsrc + boff;
      for (int bq = 0; bq < 4; ++bq) {
        const int kb = k0 + bq * 16;
        float v[16];
#pragma unroll
        for (int j = 0; j < 16; ++j) {
          if (EXP) v[j] = hp[(size_t)(kb + j) * 256];
          else     v[j] = cohld1(hp + (size_t)(kb + j) * 256);
        }
#pragma unroll
        for (int j = 0; j < 16; ++j) {
          const float4* const wr = (const float4*)(wT + (size_t)(kb + j) * 24);
          float w16[16];
          *(float4*)&w16[0] = wr[0];  *(float4*)&w16[4] = wr[1];
          *(float4*)&w16[8] = wr[2];  *(float4*)&w16[12] = wr[3];
#pragma unroll
          for (int s = 0; s < 16; ++s) ah[s] += v[j] * w16[s];
        }
      }
    }
    // ---- reduce phase1: slots 0-7 r(x+h), 8-15 u(x+h), 16-23 xh ----
#pragma unroll
    for (int c = 0; c < 8; ++c) {
      red[((size_t)(0 + c) * 8 + wv) * 66 + l] = ax[c] + ah[c];
      red[((size_t)(8 + c) * 8 + wv) * 66 + l] = ax[8 + c] + ah[8 + c];
      red[((size_t)(16 + c) * 8 + wv) * 66 + l] = ax[16 + c];
    }
    __syncthreads();
    float rp = 0, up = 0, xhp = 0;
#pragma unroll
    for (int w8 = 0; w8 < 8; ++w8) {
      rp  += red[((size_t)(0 + cq) * 8 + w8) * 66 + rr];
      up  += red[((size_t)(8 + cq) * 8 + w8) * 66 + rr];
      xhp += red[((size_t)(16 + cq) * 8 + w8) * 66 + rr];
    }
    const float rgate = sigmoidf_(rp + rbs[cq]);
    const float ug = sigmoidf_(up + ubs[cq]);
    float* const hrdst = EXP ? (hraug + (size_t)t * SLICE) : hrg;
    cohst1(hrdst + og, rgate * hcur);
    asm volatile("s_waitcnt vmcnt(0)" ::: "memory");
    __syncthreads();
    if (tid == 0)
      __hip_atomic_store(af1 + cg, (unsigned)(t + 1), __ATOMIC_RELAXED, __HIP_MEMORY_SCOPE_AGENT);
    // ---- pipelined x-dot for t+1 (hides the af1 round-trip) ----
    if (t + 1 < NL) {
      const float* const xp = big + (size_t)(t + 1) * SLICE + boff;
#pragma unroll
      for (int s = 0; s < 24; ++s) ax[s] = 0.0f;
      for (int bq = 0; bq < 4; ++bq) {
        const int kb = k0 + bq * 16;
        float v[16];
#pragma unroll
        for (int j = 0; j < 16; ++j) v[j] = xp[(size_t)(kb + j) * 256];
#pragma unroll
        for (int j = 0; j < 16; ++j) {
          const float4* const wr = (const float4*)(wT + (size_t)(512 + kb + j) * 24);
          float w24[24];
          *(float4*)&w24[0] = wr[0];  *(float4*)&w24[4] = wr[1];
          *(float4*)&w24[8] = wr[2];  *(float4*)&w24[12] = wr[3];
          *(float4*)&w24[16] = wr[4]; *(float4*)&w24[20] = wr[5];
#pragma unroll
          for (int s = 0; s < 24; ++s) ax[s] += v[j] * w24[s];
        }
      }
    }
    asm volatile("" ::: "memory");
    if (wv == 0) gwait64(af1, (unsigned)(t + 1));
    __syncthreads();
    // ---- phase2 hr-dot: hhat ----
    float ahh[8];
#pragma unroll
    for (int s = 0; s < 8; ++s) ahh[s] = 0.0f;
    {
      const float* const rp2 = (EXP ? (hraug + (size_t)t * SLICE) : hrg) + boff;
      for (int bq = 0; bq < 4; ++bq) {
        const int kb = k0 + bq * 16;
        float v[16];
#pragma unroll
        for (int j = 0; j < 16; ++j) {
          if (EXP) v[j] = rp2[(size_t)(kb + j) * 256];
          else     v[j] = cohld1(rp2 + (size_t)(kb + j) * 256);
        }
#pragma unroll
        for (int j = 0; j < 16; ++j) {
          const float4* const wr = (const float4*)(wT + (size_t)(kb + j) * 24);
          float w8a[8];
          *(float4*)&w8a[0] = wr[4];
          *(float4*)&w8a[4] = wr[5];
#pragma unroll
          for (int s = 0; s < 8; ++s) ahh[s] += v[j] * w8a[s];
        }
      }
    }
#pragma unroll
    for (int c = 0; c < 8; ++c)
      red[((size_t)c * 8 + wv) * 66 + l] = ahh[c];
    __syncthreads();
    float hhp = 0;
#pragma unroll
    for (int w8 = 0; w8 < 8; ++w8)
      hhp += red[((size_t)cq * 8 + w8) * 66 + rr];
    const float hh = tanhf(hhp + xhp + hbs[cq]);
    const float av = att[(size_t)t * 256 + r0 + rr];
    const float u = av * ug;
    const float hn = (1.0f - u) * hcur + u * hh;
    if (t == NL - 1) {
      out[(size_t)(r0 + rr) * 512 + c0 + cq] = hn;
    } else {
      float* const hdst = EXP ? (haug + (size_t)t * SLICE)
                              : (hbuf + (size_t)((t + 1) & 1) * SLICE);
      cohst1(hdst + og, hn);
    }
    asm volatile("s_waitcnt vmcnt(0)" ::: "memory");
    __syncthreads();
    if (tid == 0)
      __hip_atomic_store(af2 + cg, (unsigned)(t + 1), __ATOMIC_RELAXED, __HIP_MEMORY_SCOPE_AGENT);
  }
}

extern "C" void kernel_launch(void* const* d_in, const int* in_sizes, int n_in,
                              void* d_out, int out_size, void* d_ws, size_t ws_size,
                              hipStream_t stream) {
  (void)in_sizes; (void)n_in; (void)out_size;
  const float* session = (const float*)d_in[0];
  const float* target  = (const float*)d_in[1];
  const float* w       = (const float*)d_in[2];
  const float* wih     = (const float*)d_in[3];
  const float* whh     = (const float*)d_in[4];
  const float* bih     = (const float*)d_in[5];
  const float* bhh     = (const float*)d_in[6];
  const float* rw      = (const float*)d_in[7];
  const float* rb      = (const float*)d_in[8];
  const float* uw      = (const float*)d_in[9];
  const float* ub      = (const float*)d_in[10];
  const float* hw      = (const float*)d_in[11];
  const float* hb      = (const float*)d_in[12];
  float* ws  = (float*)d_ws;
  float* out = (float*)d_out;

  const bool expanded = ws_size >= WS_NEED_FLOATS * 4ul;

  hipLaunchKernelGGL(init_kernel, dim3(1), dim3(256), 0, stream, ws);
  hipLaunchKernelGGL(transpose_kernel, dim3(1600, 4), dim3(256), 0, stream, session, ws);
  hipLaunchKernelGGL(vt_kernel, dim3(256), dim3(256), 0, stream, w, target, ws);
  hipLaunchKernelGGL(gru_kernel, dim3(256), dim3(512), 0, stream,
                     wih, whh, bih, bhh, ws);
  hipLaunchKernelGGL(attn1_kernel, dim3(200), dim3(256), 0, stream, ws);
  hipLaunchKernelGGL(attn2_kernel, dim3(256), dim3(256), 0, stream, ws);
  if (expanded) {
    hipLaunchKernelGGL(augru_kernel<true>, dim3(256), dim3(512), 0, stream,
                       rw, rb, uw, ub, hw, hb, ws, out);
  } else {
    hipLaunchKernelGGL(augru_kernel<false>, dim3(256), dim3(512), 0, stream,
                       rw, rb, uw, ub, hw, hb, ws, out);
  }
}

// Round 13
// 7135.246 us; speedup vs baseline: 1.6229x; 1.0087x over previous
//
#include <hip/hip_runtime.h>
#include <math.h>

#define NL 200
#define SLICE 131072ul  // 512 k * 256 b floats

// ---- workspace layout (float offsets), activations stored [k][b] ----
#define BIG_OFF   0ul
#define LG_OFF    26345472ul   // logits [200][256]
#define ATT_OFF   26396672ul   // att    [200][256]
#define VT_OFF    26447872ul   // vtT    [512][256]
#define HBUF_OFF  26578944ul   // AUGRU h ping-pong [2][512][256] (fallback mode)
#define HR_OFF    26841088ul   // r*h [512][256] (fallback mode)
#define FLAGS_OFF 26972160ul   // u32 flags: gf[2][128] @0, af1[4][64] @256, af2[4][64] @512
#define HAUG_OFF  26973184ul                     // expanded: h[t]  [200][512][256]
#define HRAUG_OFF (HAUG_OFF + 200ul * SLICE)     // expanded: hr[t] [200][512][256]
#define WS_NEED_FLOATS (HRAUG_OFF + 200ul * SLICE)

typedef __attribute__((ext_vector_type(2))) __fp16 h2;  // matches fdot2 builtin type

__device__ __forceinline__ float sigmoidf_(float x) { return 1.0f / (1.0f + expf(-x)); }

// pack two f32 -> half2, RNE (unbiased)
__device__ __forceinline__ unsigned pk2(float a, float b) {
  union { h2 h; unsigned u; } x;
  x.h.x = (__fp16)a; x.h.y = (__fp16)b;
  return x.u;
}
__device__ __forceinline__ h2 pkh(float a, float b) {
  h2 r; r.x = (__fp16)a; r.y = (__fp16)b; return r;
}
// acc += dot2(a, w) with w as raw u32 half2
__device__ __forceinline__ float fd2(unsigned w, h2 a, float c) {
  union { unsigned u; h2 h; } x; x.u = w;
  return __builtin_amdgcn_fdot2(a, x.h, c, false);
}

// ---- LLC-direct (sc1) accessors: relaxed agent atomics, no fences ----
__device__ __forceinline__ float cohld1(const float* p) {
  return __hip_atomic_load(p, __ATOMIC_RELAXED, __HIP_MEMORY_SCOPE_AGENT);
}
__device__ __forceinline__ float2 cohld2(const float* p) {
  union { double d; float2 f; } u;
  u.d = __hip_atomic_load((const double*)p, __ATOMIC_RELAXED, __HIP_MEMORY_SCOPE_AGENT);
  return u.f;
}
__device__ __forceinline__ void cohst1(float* p, float v) {
  __hip_atomic_store(p, v, __ATOMIC_RELAXED, __HIP_MEMORY_SCOPE_AGENT);
}

// ---- grid waits ----
__device__ __forceinline__ void gwait64(const unsigned* f, unsigned val) {
  const int i = threadIdx.x & 63;
  int guard = 0;
  while (__hip_atomic_load(f + i, __ATOMIC_RELAXED, __HIP_MEMORY_SCOPE_AGENT) < val) {
    if (++guard > (1 << 22)) break;
  }
}
__device__ __forceinline__ void gwait128(const unsigned* f, unsigned val) {
  const int i = threadIdx.x & 63;
  bool d0 = false, d1 = false;
  int guard = 0;
  while (!(d0 && d1)) {
    if (!d0) d0 = __hip_atomic_load(f + i, __ATOMIC_RELAXED, __HIP_MEMORY_SCOPE_AGENT) >= val;
    if (!d1) d1 = __hip_atomic_load(f + i + 64, __ATOMIC_RELAXED, __HIP_MEMORY_SCOPE_AGENT) >= val;
    if (++guard > (1 << 22)) break;
  }
}

__global__ void init_kernel(float* __restrict__ ws) {
  unsigned* const fl = (unsigned*)(ws + FLAGS_OFF);
  for (int j = threadIdx.x; j < 768; j += 256) fl[j] = 0u;
}

// ---- transpose session -> BIG slices 1..200 as [k][b] (sc1 stores) ----
__global__ __launch_bounds__(256) void transpose_kernel(const float* __restrict__ in,
                                                        float* __restrict__ ws) {
  __shared__ float tile[64][65];
  const int tx = threadIdx.x & 63, ty = threadIdx.x >> 6;
  const size_t tk0 = (size_t)blockIdx.x * 64;
  const int b0 = blockIdx.y * 64;
#pragma unroll
  for (int r = 0; r < 16; ++r) {
    const int bb = ty + 4 * r;
    tile[bb][tx] = in[(size_t)(b0 + bb) * 102400 + tk0 + tx];
  }
  __syncthreads();
  float* const big1 = ws + BIG_OFF + SLICE;
#pragma unroll
  for (int r = 0; r < 16; ++r) {
    const int kk = ty + 4 * r;
    cohst1(big1 + (tk0 + kk) * 256 + b0 + tx, tile[tx][kk]);
  }
}

// ---- vtT[d][b] = sum_e w[d,e] * target[b,e] (fp32) ----
__global__ __launch_bounds__(256) void vt_kernel(const float* __restrict__ w,
                                                 const float* __restrict__ tgt,
                                                 float* __restrict__ ws) {
  __shared__ float t_s[512];
  const int b = blockIdx.x, tid = threadIdx.x;
  for (int i = tid; i < 512; i += 256) t_s[i] = tgt[(size_t)b * 512 + i];
  __syncthreads();
  const int wv = tid >> 6, lane = tid & 63;
  for (int d = wv; d < 512; d += 4) {
    const float* const wr = w + (size_t)d * 512;
    const float4 a  = *(const float4*)(wr + lane * 8);
    const float4 a2 = *(const float4*)(wr + lane * 8 + 4);
    float s = a.x * t_s[lane * 8 + 0] + a.y * t_s[lane * 8 + 1] +
              a.z * t_s[lane * 8 + 2] + a.w * t_s[lane * 8 + 3] +
              a2.x * t_s[lane * 8 + 4] + a2.y * t_s[lane * 8 + 5] +
              a2.z * t_s[lane * 8 + 6] + a2.w * t_s[lane * 8 + 7];
    for (int off = 32; off > 0; off >>= 1) s += __shfl_xor(s, off);
    if (lane == 0) ws[VT_OFF + (size_t)d * 256 + b] = s;
  }
}

// ---- persistent GRU: fp32 (r8 verbatim, passed at absmax 1.95e-3) ----
__global__ __launch_bounds__(512) void gru_kernel(const float* __restrict__ wih,
                                                  const float* __restrict__ whh,
                                                  const float* __restrict__ bih,
                                                  const float* __restrict__ bhh,
                                                  float* __restrict__ ws) {
  __shared__ float wxT[512 * 16];   // [k][16]: slot g*4+q (12 used), broadcast reads
  __shared__ float whT[512 * 16];
  __shared__ float red[16 * 8 * 130];  // [slot][wave][128 rows +2 pad]
  __shared__ float bihs[12], bhhs[12];

  const int bg = blockIdx.x >> 7;   // batch half
  const int ng = blockIdx.x & 127;  // col group
  const int b0 = bg << 7, c0 = ng << 2;
  const int tid = threadIdx.x;

  for (int i = tid; i < 512 * 16; i += 512) {
    const int k = i >> 4, s = i & 15;
    if (s < 12) {
      const int grow = ((s >> 2) << 9) + c0 + (s & 3);
      wxT[i] = wih[(size_t)grow * 512 + k];
      whT[i] = whh[(size_t)grow * 512 + k];
    }
  }
  if (tid < 12) {
    const int grow = ((tid >> 2) << 9) + c0 + (tid & 3);
    bihs[tid] = bih[grow];
    bhhs[tid] = bhh[grow];
  }
  __syncthreads();

  float* const big = ws + BIG_OFF;
  unsigned* const gf = (unsigned*)(ws + FLAGS_OFF) + (bg << 7);

  const int wv = tid >> 6, l = tid & 63;
  const int k0 = wv << 6;
  const int boff = b0 + 2 * l;          // dot-stage: rows 2l,2l+1 (float2)
  const int qg = tid >> 7;              // gate-stage: col qg, row rr
  const int rr = tid & 127;
  const size_t og = (size_t)(c0 + qg) * 256 + b0 + rr;

  // ---- prologue: x-dot for t=0 (sessionT[0] = slice 1) ----
  float2 ax[12];
#pragma unroll
  for (int s = 0; s < 12; ++s) ax[s] = make_float2(0.0f, 0.0f);
  {
    const float* const xp = big + 1ul * SLICE + boff;
    for (int bq = 0; bq < 4; ++bq) {
      const int kb = k0 + bq * 16;
      float2 v[16];
#pragma unroll
      for (int j = 0; j < 16; ++j) v[j] = cohld2(xp + (size_t)(kb + j) * 256);
#pragma unroll
      for (int j = 0; j < 16; ++j) {
        const float4* const wr = (const float4*)(wxT + (size_t)(kb + j) * 16);
        float w12[12];
        *(float4*)&w12[0] = wr[0];
        *(float4*)&w12[4] = wr[1];
        *(float4*)&w12[8] = wr[2];
#pragma unroll
        for (int s = 0; s < 12; ++s) {
          ax[s].x += v[j].x * w12[s];
          ax[s].y += v[j].y * w12[s];
        }
      }
    }
  }

  for (int t = 0; t < NL; ++t) {
    if (t > 0) {
      if (wv == 0) gwait128(gf, (unsigned)t);
      __syncthreads();
    }
    float2 ah[12];
#pragma unroll
    for (int s = 0; s < 12; ++s) ah[s] = make_float2(0.0f, 0.0f);
    float hprev = 0.0f;
    if (t > 0) {
      const float* const hp = big + (size_t)(t - 1) * SLICE + boff;
      hprev = big[(size_t)(t - 1) * SLICE + og];
      for (int bq = 0; bq < 4; ++bq) {
        const int kb = k0 + bq * 16;
        float2 v[16];
#pragma unroll
        for (int j = 0; j < 16; ++j) v[j] = *(const float2*)(hp + (size_t)(kb + j) * 256);
#pragma unroll
        for (int j = 0; j < 16; ++j) {
          const float4* const wr = (const float4*)(whT + (size_t)(kb + j) * 16);
          float w12[12];
          *(float4*)&w12[0] = wr[0];
          *(float4*)&w12[4] = wr[1];
          *(float4*)&w12[8] = wr[2];
#pragma unroll
          for (int s = 0; s < 12; ++s) {
            ah[s].x += v[j].x * w12[s];
            ah[s].y += v[j].y * w12[s];
          }
        }
      }
    }
#pragma unroll
    for (int s = 0; s < 4; ++s) {
      *(float2*)&red[((size_t)(0 + s) * 8 + wv) * 130 + 2 * l] =
          make_float2(ax[s].x + ah[s].x, ax[s].y + ah[s].y);
      *(float2*)&red[((size_t)(4 + s) * 8 + wv) * 130 + 2 * l] =
          make_float2(ax[4 + s].x + ah[4 + s].x, ax[4 + s].y + ah[4 + s].y);
      *(float2*)&red[((size_t)(8 + s) * 8 + wv) * 130 + 2 * l] = ax[8 + s];
      *(float2*)&red[((size_t)(12 + s) * 8 + wv) * 130 + 2 * l] = ah[8 + s];
    }
    __syncthreads();
    float rp = 0, zp = 0, xnp = 0, hnp = 0;
#pragma unroll
    for (int w8 = 0; w8 < 8; ++w8) {
      rp  += red[((size_t)(0 + qg) * 8 + w8) * 130 + rr];
      zp  += red[((size_t)(4 + qg) * 8 + w8) * 130 + rr];
      xnp += red[((size_t)(8 + qg) * 8 + w8) * 130 + rr];
      hnp += red[((size_t)(12 + qg) * 8 + w8) * 130 + rr];
    }
    const float r = sigmoidf_(rp + bihs[0 + qg] + bhhs[0 + qg]);
    const float z = sigmoidf_(zp + bihs[4 + qg] + bhhs[4 + qg]);
    const float n = tanhf(xnp + bihs[8 + qg] + r * (hnp + bhhs[8 + qg]));
    const float hnew = (1.0f - z) * n + z * hprev;
    cohst1(big + (size_t)t * SLICE + og, hnew);
    asm volatile("s_waitcnt vmcnt(0)" ::: "memory");
    __syncthreads();
    if (tid == 0)
      __hip_atomic_store(gf + ng, (unsigned)(t + 1), __ATOMIC_RELAXED, __HIP_MEMORY_SCOPE_AGENT);
    // ---- pipelined x-dot for t+1 ----
    if (t + 1 < NL) {
      const float* const xp = big + (size_t)(t + 2) * SLICE + boff;
#pragma unroll
      for (int s = 0; s < 12; ++s) ax[s] = make_float2(0.0f, 0.0f);
      for (int bq = 0; bq < 4; ++bq) {
        const int kb = k0 + bq * 16;
        float2 v[16];
#pragma unroll
        for (int j = 0; j < 16; ++j) v[j] = cohld2(xp + (size_t)(kb + j) * 256);
#pragma unroll
        for (int j = 0; j < 16; ++j) {
          const float4* const wr = (const float4*)(wxT + (size_t)(kb + j) * 16);
          float w12[12];
          *(float4*)&w12[0] = wr[0];
          *(float4*)&w12[4] = wr[1];
          *(float4*)&w12[8] = wr[2];
#pragma unroll
          for (int s = 0; s < 12; ++s) {
            ax[s].x += v[j].x * w12[s];
            ax[s].y += v[j].y * w12[s];
          }
        }
      }
    }
    asm volatile("" ::: "memory");
  }
}

// ---- attn1 / attn2 (fp32) ----
__global__ __launch_bounds__(256) void attn1_kernel(float* __restrict__ ws) {
  const int l = blockIdx.x, tid = threadIdx.x;
  const float* const sl = ws + BIG_OFF + (size_t)l * SLICE + tid;
  const float* const vtt = ws + VT_OFF + tid;
  float acc = 0.0f;
#pragma unroll 8
  for (int k = 0; k < 512; ++k)
    acc += sl[(size_t)k * 256] * vtt[(size_t)k * 256];
  ws[LG_OFF + (size_t)l * 256 + tid] = acc;
}

__global__ __launch_bounds__(256) void attn2_kernel(float* __restrict__ ws) {
  __shared__ float red[8];
  const int b = blockIdx.x, tid = threadIdx.x;
  const float v = (tid < NL) ? ws[LG_OFF + (size_t)tid * 256 + b] : -3.0e38f;
  float m = v;
  for (int off = 32; off > 0; off >>= 1) m = fmaxf(m, __shfl_xor(m, off));
  if ((tid & 63) == 0) red[tid >> 6] = m;
  __syncthreads();
  m = fmaxf(fmaxf(red[0], red[1]), fmaxf(red[2], red[3]));
  const float e = (tid < NL) ? expf(v - m) : 0.0f;
  float s = e;
  for (int off = 32; off > 0; off >>= 1) s += __shfl_xor(s, off);
  __syncthreads();
  if ((tid & 63) == 0) red[4 + (tid >> 6)] = s;
  __syncthreads();
  s = red[4] + red[5] + red[6] + red[7];
  if (tid < NL) ws[ATT_OFF + (size_t)tid * 256 + b] = e / s;
}

// AUGRU dot (fp16): NQ uint4 slot-groups at SOFF; activations at k-pair
// kp0+.. (ALWAYS in [0,256): one 512-k slice); weight ROW offset by WOFF
// k-pairs (256 for x-part of the [D,2D] weights, 0 for h-part).
// BUG FIX (r10-r12): folding WOFF into kp0 also offset the ACTIVATION
// address, making x-dots read sseqT[t+1] instead of sseqT[t].
template <bool COH, int NQ, int SOFF, int WOFF>
__device__ __forceinline__ void adot(const float* ap, const unsigned* wT24,
                                     int kp0, float* acc) {
  for (int g = 0; g < 4; ++g) {
    const int kb = kp0 + g * 8;
    float va[8], vb[8];
#pragma unroll
    for (int j = 0; j < 8; ++j) {
      const float* p0 = ap + (size_t)(2 * (kb + j)) * 256;
      if (COH) { va[j] = cohld1(p0); vb[j] = cohld1(p0 + 256); }
      else     { va[j] = p0[0]; vb[j] = p0[256]; }
    }
#pragma unroll
    for (int j = 0; j < 8; ++j) {
      const h2 r = pkh(va[j], vb[j]);
      const uint4* wq = (const uint4*)(wT24 + (size_t)(WOFF + kb + j) * 24) + SOFF;
#pragma unroll
      for (int q = 0; q < NQ; ++q) {
        const uint4 qq = wq[q];
        acc[4 * q + 0] = fd2(qq.x, r, acc[4 * q + 0]);
        acc[4 * q + 1] = fd2(qq.y, r, acc[4 * q + 1]);
        acc[4 * q + 2] = fd2(qq.z, r, acc[4 * q + 2]);
        acc[4 * q + 3] = fd2(qq.w, r, acc[4 * q + 3]);
      }
    }
  }
}

// ---- persistent AUGRU: split-k over 8 waves; fp16 dots ----
template <bool EXP>
__global__ __launch_bounds__(512) void augru_kernel(const float* __restrict__ rw,
                                                    const float* __restrict__ rbias,
                                                    const float* __restrict__ uw,
                                                    const float* __restrict__ ubias,
                                                    const float* __restrict__ hw,
                                                    const float* __restrict__ hbias,
                                                    float* __restrict__ ws,
                                                    float* __restrict__ out) {
  __shared__ unsigned wT[512 * 24];   // [kp][24] half2-pairs: slot m*8+c
  __shared__ float red[24 * 8 * 66];  // [slot][wave][64 rows +2 pad]
  __shared__ float rbs[8], ubs[8], hbs[8];

  const int rg = blockIdx.x >> 6;
  const int cg = blockIdx.x & 63;
  const int r0 = rg << 6, c0 = cg << 3;
  const int tid = threadIdx.x;

  for (int i = tid; i < 512 * 24; i += 512) {
    const int kp = i / 24, s = i % 24;
    const int m = s >> 3, c = s & 7;
    const float* const wm = (m == 0) ? rw : (m == 1) ? uw : hw;
    wT[i] = pk2(wm[(size_t)(c0 + c) * 1024 + 2 * kp],
                wm[(size_t)(c0 + c) * 1024 + 2 * kp + 1]);
  }
  if (tid < 8) {
    rbs[tid] = rbias[c0 + tid];
    ubs[tid] = ubias[c0 + tid];
    hbs[tid] = hbias[c0 + tid];
  }
  __syncthreads();

  float* const big = ws + BIG_OFF;
  float* const hbuf = ws + HBUF_OFF;
  float* const hrg = ws + HR_OFF;
  float* const haug = ws + HAUG_OFF;
  float* const hraug = ws + HRAUG_OFF;
  const float* const att = ws + ATT_OFF;
  unsigned* const fbase = (unsigned*)(ws + FLAGS_OFF);
  unsigned* const af1 = fbase + 256 + (rg << 6);
  unsigned* const af2 = fbase + 512 + (rg << 6);

  const int wv = tid >> 6, l = tid & 63;
  const int kp0 = wv << 5;           // this wave's k-pairs [0,256) within a slice
  const int boff = r0 + l;           // dot-stage: 1 row per lane
  const int cq = tid >> 6;           // gate-stage col
  const int rr = tid & 63;           // gate-stage row
  const size_t og = (size_t)(c0 + cq) * 256 + r0 + rr;

  // prologue: x-dot t=0 (sseqT[0], normal/L2 loads; weight rows +256)
  float ax[24];
#pragma unroll
  for (int s = 0; s < 24; ++s) ax[s] = 0.0f;
  adot<false, 6, 0, 256>(big + boff, wT, kp0, ax);

  for (int t = 0; t < NL; ++t) {
    if (t > 0) {
      if (wv == 0) gwait64(af2, (unsigned)t);
      __syncthreads();
    }
    const float* const hsrc =
        (t == 0) ? (big + 199ul * SLICE)
                 : (EXP ? (haug + (size_t)(t - 1) * SLICE)
                        : (hbuf + (size_t)(t & 1) * SLICE));
    float hcur;
    if (EXP) hcur = hsrc[og]; else hcur = cohld1(hsrc + og);
    float ah[16];
#pragma unroll
    for (int s = 0; s < 16; ++s) ah[s] = 0.0f;
    if (EXP) adot<false, 4, 0, 0>(hsrc + boff, wT, kp0, ah);
    else     adot<true, 4, 0, 0>(hsrc + boff, wT, kp0, ah);
#pragma unroll
    for (int c = 0; c < 8; ++c) {
      red[((size_t)(0 + c) * 8 + wv) * 66 + l] = ax[c] + ah[c];
      red[((size_t)(8 + c) * 8 + wv) * 66 + l] = ax[8 + c] + ah[8 + c];
      red[((size_t)(16 + c) * 8 + wv) * 66 + l] = ax[16 + c];
    }
    __syncthreads();
    float rp = 0, up = 0, xhp = 0;
#pragma unroll
    for (int w8 = 0; w8 < 8; ++w8) {
      rp  += red[((size_t)(0 + cq) * 8 + w8) * 66 + rr];
      up  += red[((size_t)(8 + cq) * 8 + w8) * 66 + rr];
      xhp += red[((size_t)(16 + cq) * 8 + w8) * 66 + rr];
    }
    const float rgate = sigmoidf_(rp + rbs[cq]);
    const float ug = sigmoidf_(up + ubs[cq]);
    float* const hrdst = EXP ? (hraug + (size_t)t * SLICE) : hrg;
    cohst1(hrdst + og, rgate * hcur);
    asm volatile("s_waitcnt vmcnt(0)" ::: "memory");
    __syncthreads();
    if (tid == 0)
      __hip_atomic_store(af1 + cg, (unsigned)(t + 1), __ATOMIC_RELAXED, __HIP_MEMORY_SCOPE_AGENT);
    // pipelined x-dot for t+1 inside the af1 window
    if (t + 1 < NL) {
#pragma unroll
      for (int s = 0; s < 24; ++s) ax[s] = 0.0f;
      adot<false, 6, 0, 256>(big + (size_t)(t + 1) * SLICE + boff, wT, kp0, ax);
    }
    asm volatile("" ::: "memory");
    if (wv == 0) gwait64(af1, (unsigned)(t + 1));
    __syncthreads();
    // phase2: hhat
    float ahh[8];
#pragma unroll
    for (int s = 0; s < 8; ++s) ahh[s] = 0.0f;
    {
      const float* const rp2 = (EXP ? (hraug + (size_t)t * SLICE) : hrg) + boff;
      if (EXP) adot<false, 2, 4, 0>(rp2, wT, kp0, ahh);
      else     adot<true, 2, 4, 0>(rp2, wT, kp0, ahh);
    }
#pragma unroll
    for (int c = 0; c < 8; ++c)
      red[((size_t)c * 8 + wv) * 66 + l] = ahh[c];
    __syncthreads();
    float hhp = 0;
#pragma unroll
    for (int w8 = 0; w8 < 8; ++w8)
      hhp += red[((size_t)cq * 8 + w8) * 66 + rr];
    const float hh = tanhf(hhp + xhp + hbs[cq]);
    const float av = att[(size_t)t * 256 + r0 + rr];
    const float u = av * ug;
    const float hn = (1.0f - u) * hcur + u * hh;
    if (t == NL - 1) {
      out[(size_t)(r0 + rr) * 512 + c0 + cq] = hn;
    } else {
      float* const hdst = EXP ? (haug + (size_t)t * SLICE)
                              : (hbuf + (size_t)((t + 1) & 1) * SLICE);
      cohst1(hdst + og, hn);
    }
    asm volatile("s_waitcnt vmcnt(0)" ::: "memory");
    __syncthreads();
    if (tid == 0)
      __hip_atomic_store(af2 + cg, (unsigned)(t + 1), __ATOMIC_RELAXED, __HIP_MEMORY_SCOPE_AGENT);
  }
}

extern "C" void kernel_launch(void* const* d_in, const int* in_sizes, int n_in,
                              void* d_out, int out_size, void* d_ws, size_t ws_size,
                              hipStream_t stream) {
  (void)in_sizes; (void)n_in; (void)out_size;
  const float* session = (const float*)d_in[0];
  const float* target  = (const float*)d_in[1];
  const float* w       = (const float*)d_in[2];
  const float* wih     = (const float*)d_in[3];
  const float* whh     = (const float*)d_in[4];
  const float* bih     = (const float*)d_in[5];
  const float* bhh     = (const float*)d_in[6];
  const float* rw      = (const float*)d_in[7];
  const float* rb      = (const float*)d_in[8];
  const float* uw      = (const float*)d_in[9];
  const float* ub      = (const float*)d_in[10];
  const float* hw      = (const float*)d_in[11];
  const float* hb      = (const float*)d_in[12];
  float* ws  = (float*)d_ws;
  float* out = (float*)d_out;

  const bool expanded = ws_size >= WS_NEED_FLOATS * 4ul;

  hipLaunchKernelGGL(init_kernel, dim3(1), dim3(256), 0, stream, ws);
  hipLaunchKernelGGL(transpose_kernel, dim3(1600, 4), dim3(256), 0, stream, session, ws);
  hipLaunchKernelGGL(vt_kernel, dim3(256), dim3(256), 0, stream, w, target, ws);
  hipLaunchKernelGGL(gru_kernel, dim3(256), dim3(512), 0, stream,
                     wih, whh, bih, bhh, ws);
  hipLaunchKernelGGL(attn1_kernel, dim3(200), dim3(256), 0, stream, ws);
  hipLaunchKernelGGL(attn2_kernel, dim3(256), dim3(256), 0, stream, ws);
  if (expanded) {
    hipLaunchKernelGGL(augru_kernel<true>, dim3(256), dim3(512), 0, stream,
                       rw, rb, uw, ub, hw, hb, ws, out);
  } else {
    hipLaunchKernelGGL(augru_kernel<false>, dim3(256), dim3(512), 0, stream,
                       rw, rb, uw, ub, hw, hb, ws, out);
  }
}